// Round 4
// baseline (4856.364 us; speedup 1.0000x reference)
//
#include <hip/hip_runtime.h>

typedef __attribute__((ext_vector_type(8))) short bf16x8;
typedef __attribute__((ext_vector_type(4))) float f32x4;
typedef unsigned short u16;

// ---------- helpers ----------
__device__ inline u16 f2b(float f) {
  union { float f; unsigned u; } x; x.f = f;
  unsigned r = x.u + 0x7FFFu + ((x.u >> 16) & 1u);
  return (u16)(r >> 16);
}
__device__ inline float b2f(u16 s) {
  union { unsigned u; float f; } x; x.u = ((unsigned)s) << 16;
  return x.f;
}
__device__ inline float gelu_f(float v) {
  return 0.5f * v * (1.0f + erff(v * 0.70710678118654752f));
}

// ---------- weight convert fp32 -> bf16 ----------
__global__ __launch_bounds__(256) void cvt_w(const float* __restrict__ s,
                                             u16* __restrict__ d, int n4) {
  int i = blockIdx.x * 256 + threadIdx.x;
  if (i < n4) {
    float4 v = ((const float4*)s)[i];
    ushort4 o; o.x = f2b(v.x); o.y = f2b(v.y); o.z = f2b(v.z); o.w = f2b(v.w);
    ((ushort4*)d)[i] = o;
  }
}

__global__ __launch_bounds__(256) void cat_bias(const float* __restrict__ a,
                                                const float* __restrict__ b,
                                                float* __restrict__ o) {
  int i = blockIdx.x * 256 + threadIdx.x;
  if (i < 1024) { o[i] = a[i]; o[1024 + i] = b[i]; }
}

// ---------- fused x->bf16 convert + 2x2x2 mean pool ----------
__global__ __launch_bounds__(256) void pool_cvt(const float* __restrict__ xg,
                                                u16* __restrict__ Xb,
                                                u16* __restrict__ Qp) {
  int qr = blockIdx.x;
  int wgi = qr & 15;
  int hgi = (qr >> 4) % 20;
  int dgi = qr / 320;
  int c = threadIdx.x * 4;
  float sx = 0.f, sy = 0.f, sz = 0.f, sw = 0.f;
#pragma unroll
  for (int j = 0; j < 8; ++j) {
    int tr = ((2 * dgi + (j >> 2)) * 40 + (2 * hgi + ((j >> 1) & 1))) * 32 +
             (2 * wgi + (j & 1));
    long off = (long)tr * 1024 + c;
    float4 v = *(const float4*)&xg[off];
    ushort4 o; o.x = f2b(v.x); o.y = f2b(v.y); o.z = f2b(v.z); o.w = f2b(v.w);
    *(ushort4*)&Xb[off] = o;
    sx += v.x; sy += v.y; sz += v.z; sw += v.w;
  }
  ushort4 o;
  o.x = f2b(sx * 0.125f); o.y = f2b(sy * 0.125f);
  o.z = f2b(sz * 0.125f); o.w = f2b(sw * 0.125f);
  *(ushort4*)&Qp[(long)qr * 1024 + c] = o;
}

// ---------- in-place LayerNorm over rows of 1024 bf16 ----------
__global__ __launch_bounds__(256) void ln_ip(u16* __restrict__ X,
                                             const float* __restrict__ w,
                                             const float* __restrict__ b) {
  long row = blockIdx.x;
  int c = threadIdx.x * 4;
  ushort4 v = *(const ushort4*)&X[row * 1024 + c];
  float f0 = b2f(v.x), f1 = b2f(v.y), f2 = b2f(v.z), f3 = b2f(v.w);
  float s = f0 + f1 + f2 + f3;
  float q = f0 * f0 + f1 * f1 + f2 * f2 + f3 * f3;
#pragma unroll
  for (int off = 32; off >= 1; off >>= 1) {
    s += __shfl_xor(s, off);
    q += __shfl_xor(q, off);
  }
  __shared__ float red[8];
  int wv = threadIdx.x >> 6, ln = threadIdx.x & 63;
  if (ln == 0) { red[wv] = s; red[4 + wv] = q; }
  __syncthreads();
  s = red[0] + red[1] + red[2] + red[3];
  q = red[4] + red[5] + red[6] + red[7];
  float mean = s * (1.f / 1024.f);
  float var = q * (1.f / 1024.f) - mean * mean;
  float rs = rsqrtf(var + 1e-6f);
  float4 wv4 = *(const float4*)&w[c];
  float4 bv4 = *(const float4*)&b[c];
  ushort4 o;
  o.x = f2b((f0 - mean) * rs * wv4.x + bv4.x);
  o.y = f2b((f1 - mean) * rs * wv4.y + bv4.y);
  o.z = f2b((f2 - mean) * rs * wv4.z + bv4.z);
  o.w = f2b((f3 - mean) * rs * wv4.w + bv4.w);
  *(ushort4*)&X[row * 1024 + c] = o;
}

// ---------- register-direct GEMM: C[M,N] = A[M,K(lda)] @ B[N,K]^T ----------
// No LDS, no barriers. Both operands K-major -> each MFMA fragment is one
// contiguous 16B global_load_dwordx4 per lane. Static 2-deep frag dbuf.
// EPI: 0 bias->bf16 ; 1 bias+gelu->bf16 ; 2 bias->fp32 ; 3 nobias->bf16
#define MFMA16(a, b, c) __builtin_amdgcn_mfma_f32_16x16x32_bf16((a), (b), (c), 0, 0, 0)

template <int EPI>
__global__ __launch_bounds__(256, 3) void gemm_rd(const u16* __restrict__ A,
                                                  const u16* __restrict__ B,
                                                  const float* __restrict__ bias,
                                                  float* __restrict__ Cf,
                                                  u16* __restrict__ Cb,
                                                  int M, int N, int K, int lda,
                                                  int nbx, int nby) {
  // XCD-aware swizzle: each XCD sweeps all bn of a contiguous bm range.
  int L = blockIdx.x, bx, by;
  if ((nbx & 7) == 0) {
    int xcd = L & 7, j = L >> 3, ppx = nbx >> 3;
    int pj = j / nby;
    bx = xcd * ppx + pj;
    by = j - pj * nby;
  } else {
    bx = L % nbx;
    by = L / nbx;
  }
  const int bm = bx * 128, bn = by * 128;

  const int l = threadIdx.x & 63, wv = threadIdx.x >> 6;
  const int wm = (wv >> 1) * 64, wn = (wv & 1) * 64;
  const int lr = l & 15, kg = l >> 4;

  const u16* pa[4];
  const u16* pb[4];
#pragma unroll
  for (int m = 0; m < 4; ++m) {
    int row = bm + wm + m * 16 + lr;
    if (row > M - 1) row = M - 1;
    pa[m] = A + (long)row * lda + kg * 8;
  }
#pragma unroll
  for (int n = 0; n < 4; ++n)
    pb[n] = B + (long)(bn + wn + n * 16 + lr) * K + kg * 8;

  f32x4 acc[4][4] = {};
  bf16x8 a0[4], b0[4], a1[4], b1[4];

#pragma unroll
  for (int m = 0; m < 4; ++m) a0[m] = *(const bf16x8*)(pa[m]);
#pragma unroll
  for (int n = 0; n < 4; ++n) b0[n] = *(const bf16x8*)(pb[n]);

  const int nt = K / 32;  // even (K = 1024 or 2048)
  for (int t = 0; t < nt; t += 2) {
    const int k1 = (t + 1) * 32, k2 = (t + 2) * 32;
    // prefetch odd step
    if (t + 1 < nt) {
#pragma unroll
      for (int m = 0; m < 4; ++m) a1[m] = *(const bf16x8*)(pa[m] + k1);
#pragma unroll
      for (int n = 0; n < 4; ++n) b1[n] = *(const bf16x8*)(pb[n] + k1);
    }
#pragma unroll
    for (int m = 0; m < 4; ++m)
#pragma unroll
      for (int n = 0; n < 4; ++n)
        acc[m][n] = MFMA16(a0[m], b0[n], acc[m][n]);
    // prefetch next even step
    if (t + 2 < nt) {
#pragma unroll
      for (int m = 0; m < 4; ++m) a0[m] = *(const bf16x8*)(pa[m] + k2);
#pragma unroll
      for (int n = 0; n < 4; ++n) b0[n] = *(const bf16x8*)(pb[n] + k2);
    }
    if (t + 1 < nt) {
#pragma unroll
      for (int m = 0; m < 4; ++m)
#pragma unroll
        for (int n = 0; n < 4; ++n)
          acc[m][n] = MFMA16(a1[m], b1[n], acc[m][n]);
    }
  }

  // ---- epilogue ----
#pragma unroll
  for (int m = 0; m < 4; ++m) {
    int row0 = bm + wm + m * 16 + kg * 4;
#pragma unroll
    for (int n = 0; n < 4; ++n) {
      int col = bn + wn + n * 16 + lr;
      float bsv = (EPI == 3) ? 0.f : bias[col];
#pragma unroll
      for (int r = 0; r < 4; ++r) {
        int row = row0 + r;
        if (row < M) {
          float v = acc[m][n][r] + bsv;
          if (EPI == 1) v = gelu_f(v);
          if (EPI == 2) Cf[(long)row * N + col] = v;
          else Cb[(long)row * N + col] = f2b(v);
        }
      }
    }
  }
}

// ---------- 8-key local attention ----------
__global__ __launch_bounds__(256) void attn_k(const u16* __restrict__ QH,
                                              const u16* __restrict__ KH,
                                              const u16* __restrict__ VH,
                                              u16* __restrict__ O) {
  int qr = blockIdx.x;
  int wgi = qr & 15;
  int hgi = (qr >> 4) % 20;
  int dgi = qr / 320;
  int c0 = (threadIdx.x >> 5) * 128 + (threadIdx.x & 31) * 4;
  ushort4 qv = *(const ushort4*)&QH[(long)qr * 1024 + c0];
  float q0 = b2f(qv.x), q1 = b2f(qv.y), q2 = b2f(qv.z), q3 = b2f(qv.w);
  long trs[8];
  float sc[8];
#pragma unroll
  for (int j = 0; j < 8; ++j) {
    int tr = ((2 * dgi + (j >> 2)) * 40 + (2 * hgi + ((j >> 1) & 1))) * 32 +
             (2 * wgi + (j & 1));
    trs[j] = (long)tr * 1024 + c0;
    ushort4 kv = *(const ushort4*)&KH[trs[j]];
    float p = q0 * b2f(kv.x) + q1 * b2f(kv.y) + q2 * b2f(kv.z) + q3 * b2f(kv.w);
    p += __shfl_xor(p, 16); p += __shfl_xor(p, 8); p += __shfl_xor(p, 4);
    p += __shfl_xor(p, 2);  p += __shfl_xor(p, 1);
    sc[j] = p * 0.088388347648318447f;  // 1/sqrt(128)
  }
  float mx = sc[0];
#pragma unroll
  for (int j = 1; j < 8; ++j) mx = fmaxf(mx, sc[j]);
  float ssum = 0.f;
#pragma unroll
  for (int j = 0; j < 8; ++j) { sc[j] = expf(sc[j] - mx); ssum += sc[j]; }
  float inv = 1.0f / ssum;
  float o0 = 0, o1 = 0, o2 = 0, o3 = 0;
#pragma unroll
  for (int j = 0; j < 8; ++j) {
    ushort4 vv = *(const ushort4*)&VH[trs[j]];
    float p = sc[j] * inv;
    o0 += p * b2f(vv.x); o1 += p * b2f(vv.y);
    o2 += p * b2f(vv.z); o3 += p * b2f(vv.w);
  }
  ushort4 ov; ov.x = f2b(o0); ov.y = f2b(o1); ov.z = f2b(o2); ov.w = f2b(o3);
  *(ushort4*)&O[(long)qr * 1024 + c0] = ov;
}

// ---------- host ----------
extern "C" void kernel_launch(void* const* d_in, const int* in_sizes, int n_in,
                              void* d_out, int out_size, void* d_ws,
                              size_t ws_size, hipStream_t stream) {
  const float* x      = (const float*)d_in[0];
  const float* q_w    = (const float*)d_in[1];
  const float* k_w1   = (const float*)d_in[2];
  const float* k_b1   = (const float*)d_in[3];
  const float* k_w2   = (const float*)d_in[4];
  const float* k_b2   = (const float*)d_in[5];
  const float* v_w1   = (const float*)d_in[6];
  const float* v_b1   = (const float*)d_in[7];
  const float* v_w2   = (const float*)d_in[8];
  const float* v_b2   = (const float*)d_in[9];
  const float* lnq_w  = (const float*)d_in[10];
  const float* lnq_b  = (const float*)d_in[11];
  const float* lnk_w  = (const float*)d_in[12];
  const float* lnk_b  = (const float*)d_in[13];
  const float* lnv_w  = (const float*)d_in[14];
  const float* lnv_b  = (const float*)d_in[15];
  const float* in_w   = (const float*)d_in[16];
  const float* in_b   = (const float*)d_in[17];
  const float* out_w  = (const float*)d_in[18];
  const float* out_b  = (const float*)d_in[19];
  const float* mlp_w1 = (const float*)d_in[20];
  const float* mlp_b1 = (const float*)d_in[21];
  const float* mlp_w2 = (const float*)d_in[22];
  const float* mlp_b2 = (const float*)d_in[23];
  float* out = (float*)d_out;

  char* base = (char*)d_ws;
  size_t off = 0;
  auto alloc_us = [&](size_t elems) -> u16* {
    u16* r = (u16*)(base + off);
    off += ((elems * 2 + 255) & ~(size_t)255);
    return r;
  };
  const size_t CC = 1024 * 1024;
  u16* wb_q   = alloc_us(CC);
  u16* wb_kv1 = alloc_us(2 * CC);
  u16* wb_k2  = alloc_us(CC);
  u16* wb_v2  = alloc_us(CC);
  u16* wb_in  = alloc_us(3 * CC);
  u16* wb_out = alloc_us(CC);
  u16* wb_m1  = alloc_us(2 * CC);
  u16* wb_m2  = alloc_us(4 * CC);
  float* b_kv1 = (float*)(base + off); off += 2048 * 4;

  auto cvt = [&](const float* s, u16* d, size_t n) {
    int n4 = (int)(n / 4);
    cvt_w<<<(n4 + 255) / 256, 256, 0, stream>>>(s, d, n4);
  };
  cvt(q_w, wb_q, CC);
  cvt(k_w1, wb_kv1, CC);        cvt(v_w1, wb_kv1 + CC, CC);
  cvt(k_w2, wb_k2, CC);         cvt(v_w2, wb_v2, CC);
  cvt(in_w, wb_in, 3 * CC);     cvt(out_w, wb_out, CC);
  cvt(mlp_w1, wb_m1, 2 * CC);   cvt(mlp_w2, wb_m2, 4 * CC);
  cat_bias<<<4, 256, 0, stream>>>(k_b1, v_b1, b_kv1);

  int s = 16;
  for (int cand = 1; cand <= 16; cand <<= 1) {
    size_t Tc_ = 40960ull / cand;
    size_t need = off + Tc_ * 11520ull + (1ull << 20);
    if (need <= ws_size) { s = cand; break; }
  }
  const int dcount = 32 / s;
  const int dgc = dcount / 2;
  const int Tc = dcount * 1280;
  const int Tq = dgc * 320;

  u16* Xb  = alloc_us((size_t)Tc * 1024);
  u16* Hb2 = alloc_us((size_t)Tc * 2048);
  u16* Kb  = alloc_us((size_t)Tc * 1024);
  u16* Vb  = alloc_us((size_t)Tc * 1024);
  u16* Qp  = alloc_us((size_t)Tq * 1024);
  u16* QQ  = alloc_us((size_t)Tq * 1024);
  u16* QHb = alloc_us((size_t)Tq * 1024);
  u16* Ob  = alloc_us((size_t)Tq * 1024);
  u16* O2  = alloc_us((size_t)Tq * 1024);
  u16* Hm  = Kb;

  auto launch_gemm = [&](int EPI, const u16* A, const u16* B, const float* bias,
                         float* Cf, u16* Cb, int M, int N, int K, int lda) {
    int nbx = (M + 127) / 128, nby = N / 128;
    dim3 g(nbx * nby);
    switch (EPI) {
      case 0: gemm_rd<0><<<g, 256, 0, stream>>>(A, B, bias, Cf, Cb, M, N, K, lda, nbx, nby); break;
      case 1: gemm_rd<1><<<g, 256, 0, stream>>>(A, B, bias, Cf, Cb, M, N, K, lda, nbx, nby); break;
      case 2: gemm_rd<2><<<g, 256, 0, stream>>>(A, B, bias, Cf, Cb, M, N, K, lda, nbx, nby); break;
      default: gemm_rd<3><<<g, 256, 0, stream>>>(A, B, bias, Cf, Cb, M, N, K, lda, nbx, nby); break;
    }
  };

  for (int n = 0; n < 2; ++n) {
    for (int sl = 0; sl < s; ++sl) {
      long tok0 = (long)n * 40960 + (long)sl * dcount * 1280;
      long q0g  = (long)n * 5120 + (long)sl * dgc * 320;
      const float* xg = x + tok0 * 1024;

      pool_cvt<<<Tq, 256, 0, stream>>>(xg, Xb, Qp);

      launch_gemm(1, Xb, wb_kv1, b_kv1, nullptr, Hb2, Tc, 2048, 1024, 1024);
      launch_gemm(0, Hb2, wb_k2, k_b2, nullptr, Kb, Tc, 1024, 1024, 2048);
      ln_ip<<<Tc, 256, 0, stream>>>(Kb, lnk_w, lnk_b);
      launch_gemm(0, Hb2 + 1024, wb_v2, v_b2, nullptr, Vb, Tc, 1024, 1024, 2048);
      ln_ip<<<Tc, 256, 0, stream>>>(Vb, lnv_w, lnv_b);

      launch_gemm(3, Qp, wb_q, nullptr, nullptr, QQ, Tq, 1024, 1024, 1024);
      ln_ip<<<Tq, 256, 0, stream>>>(QQ, lnq_w, lnq_b);
      launch_gemm(0, QQ, wb_in, in_b, nullptr, QHb, Tq, 1024, 1024, 1024);

      launch_gemm(0, Kb, wb_in + CC, in_b + 1024, nullptr, Xb, Tc, 1024, 1024, 1024);
      launch_gemm(0, Vb, wb_in + 2 * CC, in_b + 2048, nullptr, Hb2, Tc, 1024, 1024, 1024);

      attn_k<<<Tq, 256, 0, stream>>>(QHb, Xb, Hb2, Ob);

      launch_gemm(0, Ob, wb_out, out_b, nullptr, O2, Tq, 1024, 1024, 1024);
      launch_gemm(1, O2, wb_m1, mlp_b1, nullptr, Hm, Tq, 2048, 1024, 1024);
      launch_gemm(2, Hm, wb_m2, mlp_b2, out + q0g * 2048, nullptr, Tq, 2048, 2048, 2048);
    }
  }
}

// Round 5
// 2460.948 us; speedup vs baseline: 1.9734x; 1.9734x over previous
//
#include <hip/hip_runtime.h>

typedef __attribute__((ext_vector_type(8))) short bf16x8;
typedef __attribute__((ext_vector_type(4))) float f32x4;
typedef unsigned short u16;

// ---------- helpers ----------
__device__ inline u16 f2b(float f) {
  union { float f; unsigned u; } x; x.f = f;
  unsigned r = x.u + 0x7FFFu + ((x.u >> 16) & 1u);
  return (u16)(r >> 16);
}
__device__ inline float b2f(u16 s) {
  union { unsigned u; float f; } x; x.u = ((unsigned)s) << 16;
  return x.f;
}
__device__ inline float gelu_f(float v) {
  return 0.5f * v * (1.0f + erff(v * 0.70710678118654752f));
}
__device__ inline void gll16(const void* g, void* lds) {
  __builtin_amdgcn_global_load_lds((const __attribute__((address_space(1))) void*)g,
                                   (__attribute__((address_space(3))) void*)lds,
                                   16, 0, 0);
}

// ---------- weight convert fp32 -> bf16 ----------
__global__ __launch_bounds__(256) void cvt_w(const float* __restrict__ s,
                                             u16* __restrict__ d, int n4) {
  int i = blockIdx.x * 256 + threadIdx.x;
  if (i < n4) {
    float4 v = ((const float4*)s)[i];
    ushort4 o; o.x = f2b(v.x); o.y = f2b(v.y); o.z = f2b(v.z); o.w = f2b(v.w);
    ((ushort4*)d)[i] = o;
  }
}

__global__ __launch_bounds__(256) void cat_bias(const float* __restrict__ a,
                                                const float* __restrict__ b,
                                                float* __restrict__ o) {
  int i = blockIdx.x * 256 + threadIdx.x;
  if (i < 1024) { o[i] = a[i]; o[1024 + i] = b[i]; }
}

// ---------- fused x->bf16 convert + 2x2x2 mean pool ----------
__global__ __launch_bounds__(256) void pool_cvt(const float* __restrict__ xg,
                                                u16* __restrict__ Xb,
                                                u16* __restrict__ Qp) {
  int qr = blockIdx.x;
  int wgi = qr & 15;
  int hgi = (qr >> 4) % 20;
  int dgi = qr / 320;
  int c = threadIdx.x * 4;
  float sx = 0.f, sy = 0.f, sz = 0.f, sw = 0.f;
#pragma unroll
  for (int j = 0; j < 8; ++j) {
    int tr = ((2 * dgi + (j >> 2)) * 40 + (2 * hgi + ((j >> 1) & 1))) * 32 +
             (2 * wgi + (j & 1));
    long off = (long)tr * 1024 + c;
    float4 v = *(const float4*)&xg[off];
    ushort4 o; o.x = f2b(v.x); o.y = f2b(v.y); o.z = f2b(v.z); o.w = f2b(v.w);
    *(ushort4*)&Xb[off] = o;
    sx += v.x; sy += v.y; sz += v.z; sw += v.w;
  }
  ushort4 o;
  o.x = f2b(sx * 0.125f); o.y = f2b(sy * 0.125f);
  o.z = f2b(sz * 0.125f); o.w = f2b(sw * 0.125f);
  *(ushort4*)&Qp[(long)qr * 1024 + c] = o;
}

// ---------- in-place LayerNorm over rows of 1024 bf16 ----------
__global__ __launch_bounds__(256) void ln_ip(u16* __restrict__ X,
                                             const float* __restrict__ w,
                                             const float* __restrict__ b) {
  long row = blockIdx.x;
  int c = threadIdx.x * 4;
  ushort4 v = *(const ushort4*)&X[row * 1024 + c];
  float f0 = b2f(v.x), f1 = b2f(v.y), f2 = b2f(v.z), f3 = b2f(v.w);
  float s = f0 + f1 + f2 + f3;
  float q = f0 * f0 + f1 * f1 + f2 * f2 + f3 * f3;
#pragma unroll
  for (int off = 32; off >= 1; off >>= 1) {
    s += __shfl_xor(s, off);
    q += __shfl_xor(q, off);
  }
  __shared__ float red[8];
  int wv = threadIdx.x >> 6, ln = threadIdx.x & 63;
  if (ln == 0) { red[wv] = s; red[4 + wv] = q; }
  __syncthreads();
  s = red[0] + red[1] + red[2] + red[3];
  q = red[4] + red[5] + red[6] + red[7];
  float mean = s * (1.f / 1024.f);
  float var = q * (1.f / 1024.f) - mean * mean;
  float rs = rsqrtf(var + 1e-6f);
  float4 wv4 = *(const float4*)&w[c];
  float4 bv4 = *(const float4*)&b[c];
  ushort4 o;
  o.x = f2b((f0 - mean) * rs * wv4.x + bv4.x);
  o.y = f2b((f1 - mean) * rs * wv4.y + bv4.y);
  o.z = f2b((f2 - mean) * rs * wv4.z + bv4.z);
  o.w = f2b((f3 - mean) * rs * wv4.w + bv4.w);
  *(ushort4*)&X[row * 1024 + c] = o;
}

#define MFMA16(a, b, c) __builtin_amdgcn_mfma_f32_16x16x32_bf16((a), (b), (c), 0, 0, 0)

// ---------- 128x128 2-phase GEMM (round-2 verified) ----------
// EPI: 0 bias->bf16 ; 1 bias+gelu->bf16 ; 2 bias->fp32 ; 3 nobias->bf16
#define BK 32
template <int EPI>
__global__ __launch_bounds__(256) void gemm_bt(const u16* __restrict__ A,
                                               const u16* __restrict__ B,
                                               const float* __restrict__ bias,
                                               float* __restrict__ Cf,
                                               u16* __restrict__ Cb,
                                               int M, int N, int K, int lda,
                                               int nbx, int nby) {
  __shared__ __align__(16) u16 As0[128 * BK];
  __shared__ __align__(16) u16 Bs0[128 * BK];
  __shared__ __align__(16) u16 As1[128 * BK];
  __shared__ __align__(16) u16 Bs1[128 * BK];
  const int tid = threadIdx.x;

  int L = blockIdx.x, bx, by;
  if ((nbx & 7) == 0) {
    int xcd = L & 7, j = L >> 3, ppx = nbx >> 3;
    int pj = j / nby;
    bx = xcd * ppx + pj;
    by = j - pj * nby;
  } else {
    bx = L % nbx;
    by = L / nbx;
  }
  const int bm = bx * 128, bn = by * 128;

  const int l = tid & 63, wv = tid >> 6;
  const int wm = (wv >> 1) * 64, wn = (wv & 1) * 64;
  const int lr = l & 15, kg = l >> 4;

  const int ea = tid * 8, eb = (256 + tid) * 8;
  const int ra = ea >> 5, ca = ea & 31;
  const int rb = eb >> 5, cbn = eb & 31;
  int gra = bm + ra; if (gra > M - 1) gra = M - 1;
  int grb = bm + rb; if (grb > M - 1) grb = M - 1;
  const u16* pa0 = A + (long)gra * lda + ca;
  const u16* pa1 = A + (long)grb * lda + cbn;
  const u16* pb0 = B + (long)(bn + ra) * K + ca;
  const u16* pb1 = B + (long)(bn + rb) * K + cbn;

  f32x4 acc[4][4] = {};
  const int nt = K / BK;

#define STAGE(AS, BS, k0)                \
  do {                                   \
    gll16(pa0 + (k0), &(AS)[ea]);        \
    gll16(pb0 + (k0), &(BS)[ea]);        \
    gll16(pa1 + (k0), &(AS)[eb]);        \
    gll16(pb1 + (k0), &(BS)[eb]);        \
  } while (0)

#define COMPUTE(AS, BS)                                                       \
  do {                                                                        \
    bf16x8 af[4], bfr[4];                                                     \
    _Pragma("unroll") for (int m = 0; m < 4; ++m)                             \
        af[m] = *(const bf16x8*)&(AS)[(wm + m * 16 + lr) * BK + kg * 8];      \
    _Pragma("unroll") for (int n = 0; n < 4; ++n)                             \
        bfr[n] = *(const bf16x8*)&(BS)[(wn + n * 16 + lr) * BK + kg * 8];     \
    _Pragma("unroll") for (int m = 0; m < 4; ++m)                             \
        _Pragma("unroll") for (int n = 0; n < 4; ++n)                         \
            acc[m][n] = MFMA16(af[m], bfr[n], acc[m][n]);                     \
  } while (0)

  STAGE(As0, Bs0, 0);
  __syncthreads();
  for (int t = 0; t < nt; t += 2) {
    if (t + 1 < nt) STAGE(As1, Bs1, (t + 1) * BK);
    COMPUTE(As0, Bs0);
    __syncthreads();
    if (t + 2 < nt) STAGE(As0, Bs0, (t + 2) * BK);
    COMPUTE(As1, Bs1);
    __syncthreads();
  }
#undef STAGE
#undef COMPUTE

#pragma unroll
  for (int m = 0; m < 4; ++m) {
    int row0 = bm + wm + m * 16 + kg * 4;
#pragma unroll
    for (int n = 0; n < 4; ++n) {
      int col = bn + wn + n * 16 + lr;
      float bsv = (EPI == 3) ? 0.f : bias[col];
#pragma unroll
      for (int r = 0; r < 4; ++r) {
        int row = row0 + r;
        if (row < M) {
          float v = acc[m][n][r] + bsv;
          if (EPI == 1) v = gelu_f(v);
          if (EPI == 2) Cf[(long)row * N + col] = v;
          else Cb[(long)row * N + col] = f2b(v);
        }
      }
    }
  }
}

// ---------- 256x256 2-phase GEMM, BK=64, 512 thr, 128KB dbuf LDS ----------
// Staging/swizzle/epilogue geometry = round-3 verified; schedule = simple
// 2-phase (STAGE(next); COMPUTE(cur); __syncthreads) per m230-V0 recipe.
// LDS map: [A(p=0)][B(p=0)][A(p=1)][B(p=1)], each tile 16384 u16 (256x64).
template <int EPI>
__global__ __launch_bounds__(512, 2) void g256(const u16* __restrict__ A,
                                               const u16* __restrict__ B,
                                               const float* __restrict__ bias,
                                               float* __restrict__ Cf,
                                               u16* __restrict__ Cb,
                                               int M, int N, int K, int lda,
                                               int nbx, int nby) {
  extern __shared__ u16 lds[];
  const int tid = threadIdx.x;
  const int l = tid & 63, w = tid >> 6;
  const int wr = w >> 2, wc = w & 3;
  const int lr = l & 15, kg = l >> 4;

  int L = blockIdx.x, bx, by;
  if ((nbx & 7) == 0) {
    int xcd = L & 7, j = L >> 3, ppx = nbx >> 3;
    int pj = j / nby;
    bx = xcd * ppx + pj;
    by = j - pj * nby;
  } else {
    bx = L % nbx;
    by = L / nbx;
  }
  const int bm = bx * 256, bn = by * 256;

  // staging geometry (per 128x64 half: 1024 chunks of 16B)
  const int c0 = w * 64 + l, c1 = 512 + c0;
  const int r0 = c0 >> 3, cs0 = (c0 & 7) ^ (r0 & 7);
  const int r1 = c1 >> 3, cs1 = (c1 & 7) ^ (r1 & 7);
  const u16* Ab = A + (long)bm * lda;
  const u16* Bb = B + (long)bn * K;
  int a0r0 = min(bm + r0, M - 1) - bm;
  int a0r1 = min(bm + r1, M - 1) - bm;
  int a1r0 = min(bm + 128 + r0, M - 1) - bm;
  int a1r1 = min(bm + 128 + r1, M - 1) - bm;
  const int oA00 = a0r0 * lda + cs0 * 8, oA01 = a0r1 * lda + cs1 * 8;
  const int oA10 = a1r0 * lda + cs0 * 8, oA11 = a1r1 * lda + cs1 * 8;
  const int oB00 = r0 * K + cs0 * 8, oB01 = r1 * K + cs1 * 8;
  const int oB10 = (128 + r0) * K + cs0 * 8, oB11 = (128 + r1) * K + cs1 * 8;
  const int d0 = c0 * 8, d1 = c1 * 8;

  // swizzled ds_read chunk offsets (elems) for ks=0,1
  const int sw0 = ((kg) ^ (l & 7)) * 8;
  const int sw1 = ((4 + kg) ^ (l & 7)) * 8;

  const int rA = wr * 64 + lr;               // row within each A half
  const int rB = (wc & 1) * 64 + lr;         // row within wave's B half
  const int bhalf = (wc >> 1) * 8192;        // wave's B half offset

  f32x4 acc[8][4] = {};
  const int nt = K / 64;

#define STG(P, ko)                                                   \
  do {                                                               \
    u16* ap = lds + (P) * 32768;                                     \
    u16* bp = lds + 16384 + (P) * 32768;                             \
    gll16(Ab + oA00 + (ko), ap + d0);                                \
    gll16(Ab + oA01 + (ko), ap + d1);                                \
    gll16(Ab + oA10 + (ko), ap + 8192 + d0);                         \
    gll16(Ab + oA11 + (ko), ap + 8192 + d1);                         \
    gll16(Bb + oB00 + (ko), bp + d0);                                \
    gll16(Bb + oB01 + (ko), bp + d1);                                \
    gll16(Bb + oB10 + (ko), bp + 8192 + d0);                         \
    gll16(Bb + oB11 + (ko), bp + 8192 + d1);                         \
  } while (0)

#define CMP(P)                                                                 \
  do {                                                                         \
    const u16* ap = lds + (P) * 32768;                                         \
    const u16* bp = lds + 16384 + (P) * 32768 + bhalf;                         \
    bf16x8 af[4][2], bfr[4][2];                                                \
    _Pragma("unroll") for (int nn = 0; nn < 4; ++nn) {                         \
      bfr[nn][0] = *(const bf16x8*)&bp[(rB + nn * 16) * 64 + sw0];             \
      bfr[nn][1] = *(const bf16x8*)&bp[(rB + nn * 16) * 64 + sw1];             \
    }                                                                          \
    _Pragma("unroll") for (int mq = 0; mq < 4; ++mq) {                         \
      af[mq][0] = *(const bf16x8*)&ap[(rA + mq * 16) * 64 + sw0];              \
      af[mq][1] = *(const bf16x8*)&ap[(rA + mq * 16) * 64 + sw1];              \
    }                                                                          \
    _Pragma("unroll") for (int mq = 0; mq < 4; ++mq)                           \
      _Pragma("unroll") for (int nn = 0; nn < 4; ++nn) {                       \
        acc[mq][nn] = MFMA16(af[mq][0], bfr[nn][0], acc[mq][nn]);              \
        acc[mq][nn] = MFMA16(af[mq][1], bfr[nn][1], acc[mq][nn]);              \
      }                                                                        \
    _Pragma("unroll") for (int mq = 0; mq < 4; ++mq) {                         \
      af[mq][0] = *(const bf16x8*)&ap[8192 + (rA + mq * 16) * 64 + sw0];       \
      af[mq][1] = *(const bf16x8*)&ap[8192 + (rA + mq * 16) * 64 + sw1];       \
    }                                                                          \
    _Pragma("unroll") for (int mq = 0; mq < 4; ++mq)                           \
      _Pragma("unroll") for (int nn = 0; nn < 4; ++nn) {                       \
        acc[4 + mq][nn] = MFMA16(af[mq][0], bfr[nn][0], acc[4 + mq][nn]);      \
        acc[4 + mq][nn] = MFMA16(af[mq][1], bfr[nn][1], acc[4 + mq][nn]);      \
      }                                                                        \
  } while (0)

  STG(0, 0);
  __syncthreads();
  for (int t = 0; t < nt; t += 2) {
    if (t + 1 < nt) STG(1, (t + 1) * 64);
    CMP(0);
    __syncthreads();
    if (t + 2 < nt) STG(0, (t + 2) * 64);
    CMP(1);
    __syncthreads();
  }
#undef STG
#undef CMP

  // ---- epilogue (round-3 verified mapping) ----
#pragma unroll
  for (int m = 0; m < 8; ++m) {
    int row = bm + (m >> 2) * 128 + wr * 64 + (m & 3) * 16 + kg * 4;
#pragma unroll
    for (int n = 0; n < 4; ++n) {
      int col = bn + wc * 64 + n * 16 + lr;
      float bsv = (EPI == 3) ? 0.f : bias[col];
#pragma unroll
      for (int r = 0; r < 4; ++r) {
        if (row + r < M) {
          float v = acc[m][n][r] + bsv;
          if (EPI == 1) v = gelu_f(v);
          if (EPI == 2) Cf[(long)(row + r) * N + col] = v;
          else Cb[(long)(row + r) * N + col] = f2b(v);
        }
      }
    }
  }
}

// ---------- 8-key local attention ----------
__global__ __launch_bounds__(256) void attn_k(const u16* __restrict__ QH,
                                              const u16* __restrict__ KH,
                                              const u16* __restrict__ VH,
                                              u16* __restrict__ O) {
  int qr = blockIdx.x;
  int wgi = qr & 15;
  int hgi = (qr >> 4) % 20;
  int dgi = qr / 320;
  int c0 = (threadIdx.x >> 5) * 128 + (threadIdx.x & 31) * 4;
  ushort4 qv = *(const ushort4*)&QH[(long)qr * 1024 + c0];
  float q0 = b2f(qv.x), q1 = b2f(qv.y), q2 = b2f(qv.z), q3 = b2f(qv.w);
  long trs[8];
  float sc[8];
#pragma unroll
  for (int j = 0; j < 8; ++j) {
    int tr = ((2 * dgi + (j >> 2)) * 40 + (2 * hgi + ((j >> 1) & 1))) * 32 +
             (2 * wgi + (j & 1));
    trs[j] = (long)tr * 1024 + c0;
    ushort4 kv = *(const ushort4*)&KH[trs[j]];
    float p = q0 * b2f(kv.x) + q1 * b2f(kv.y) + q2 * b2f(kv.z) + q3 * b2f(kv.w);
    p += __shfl_xor(p, 16); p += __shfl_xor(p, 8); p += __shfl_xor(p, 4);
    p += __shfl_xor(p, 2);  p += __shfl_xor(p, 1);
    sc[j] = p * 0.088388347648318447f;  // 1/sqrt(128)
  }
  float mx = sc[0];
#pragma unroll
  for (int j = 1; j < 8; ++j) mx = fmaxf(mx, sc[j]);
  float ssum = 0.f;
#pragma unroll
  for (int j = 0; j < 8; ++j) { sc[j] = expf(sc[j] - mx); ssum += sc[j]; }
  float inv = 1.0f / ssum;
  float o0 = 0, o1 = 0, o2 = 0, o3 = 0;
#pragma unroll
  for (int j = 0; j < 8; ++j) {
    ushort4 vv = *(const ushort4*)&VH[trs[j]];
    float p = sc[j] * inv;
    o0 += p * b2f(vv.x); o1 += p * b2f(vv.y);
    o2 += p * b2f(vv.z); o3 += p * b2f(vv.w);
  }
  ushort4 ov; ov.x = f2b(o0); ov.y = f2b(o1); ov.z = f2b(o2); ov.w = f2b(o3);
  *(ushort4*)&O[(long)qr * 1024 + c0] = ov;
}

// ---------- host ----------
extern "C" void kernel_launch(void* const* d_in, const int* in_sizes, int n_in,
                              void* d_out, int out_size, void* d_ws,
                              size_t ws_size, hipStream_t stream) {
  const float* x      = (const float*)d_in[0];
  const float* q_w    = (const float*)d_in[1];
  const float* k_w1   = (const float*)d_in[2];
  const float* k_b1   = (const float*)d_in[3];
  const float* k_w2   = (const float*)d_in[4];
  const float* k_b2   = (const float*)d_in[5];
  const float* v_w1   = (const float*)d_in[6];
  const float* v_b1   = (const float*)d_in[7];
  const float* v_w2   = (const float*)d_in[8];
  const float* v_b2   = (const float*)d_in[9];
  const float* lnq_w  = (const float*)d_in[10];
  const float* lnq_b  = (const float*)d_in[11];
  const float* lnk_w  = (const float*)d_in[12];
  const float* lnk_b  = (const float*)d_in[13];
  const float* lnv_w  = (const float*)d_in[14];
  const float* lnv_b  = (const float*)d_in[15];
  const float* in_w   = (const float*)d_in[16];
  const float* in_b   = (const float*)d_in[17];
  const float* out_w  = (const float*)d_in[18];
  const float* out_b  = (const float*)d_in[19];
  const float* mlp_w1 = (const float*)d_in[20];
  const float* mlp_b1 = (const float*)d_in[21];
  const float* mlp_w2 = (const float*)d_in[22];
  const float* mlp_b2 = (const float*)d_in[23];
  float* out = (float*)d_out;

  hipFuncSetAttribute((const void*)g256<0>, hipFuncAttributeMaxDynamicSharedMemorySize, 131072);
  hipFuncSetAttribute((const void*)g256<1>, hipFuncAttributeMaxDynamicSharedMemorySize, 131072);
  hipFuncSetAttribute((const void*)g256<2>, hipFuncAttributeMaxDynamicSharedMemorySize, 131072);
  hipFuncSetAttribute((const void*)g256<3>, hipFuncAttributeMaxDynamicSharedMemorySize, 131072);

  char* base = (char*)d_ws;
  size_t off = 0;
  auto alloc_us = [&](size_t elems) -> u16* {
    u16* r = (u16*)(base + off);
    off += ((elems * 2 + 255) & ~(size_t)255);
    return r;
  };
  const size_t CC = 1024 * 1024;
  u16* wb_q   = alloc_us(CC);
  u16* wb_kv1 = alloc_us(2 * CC);
  u16* wb_k2  = alloc_us(CC);
  u16* wb_v2  = alloc_us(CC);
  u16* wb_in  = alloc_us(3 * CC);
  u16* wb_out = alloc_us(CC);
  u16* wb_m1  = alloc_us(2 * CC);
  u16* wb_m2  = alloc_us(4 * CC);
  float* b_kv1 = (float*)(base + off); off += 2048 * 4;

  auto cvt = [&](const float* s, u16* d, size_t n) {
    int n4 = (int)(n / 4);
    cvt_w<<<(n4 + 255) / 256, 256, 0, stream>>>(s, d, n4);
  };
  cvt(q_w, wb_q, CC);
  cvt(k_w1, wb_kv1, CC);        cvt(v_w1, wb_kv1 + CC, CC);
  cvt(k_w2, wb_k2, CC);         cvt(v_w2, wb_v2, CC);
  cvt(in_w, wb_in, 3 * CC);     cvt(out_w, wb_out, CC);
  cvt(mlp_w1, wb_m1, 2 * CC);   cvt(mlp_w2, wb_m2, 4 * CC);
  cat_bias<<<4, 256, 0, stream>>>(k_b1, v_b1, b_kv1);

  int s = 16;
  for (int cand = 1; cand <= 16; cand <<= 1) {
    size_t Tc_ = 40960ull / cand;
    size_t need = off + Tc_ * 11520ull + (1ull << 20);
    if (need <= ws_size) { s = cand; break; }
  }
  const int dcount = 32 / s;
  const int dgc = dcount / 2;
  const int Tc = dcount * 1280;
  const int Tq = dgc * 320;

  u16* Xb  = alloc_us((size_t)Tc * 1024);
  u16* Hb2 = alloc_us((size_t)Tc * 2048);
  u16* Kb  = alloc_us((size_t)Tc * 1024);
  u16* Vb  = alloc_us((size_t)Tc * 1024);
  u16* Qp  = alloc_us((size_t)Tq * 1024);
  u16* QQ  = alloc_us((size_t)Tq * 1024);
  u16* QHb = alloc_us((size_t)Tq * 1024);
  u16* Ob  = alloc_us((size_t)Tq * 1024);
  u16* O2  = alloc_us((size_t)Tq * 1024);
  u16* Hm  = Kb;

  auto launch_gemm = [&](int EPI, const u16* A, const u16* B, const float* bias,
                         float* Cf, u16* Cb, int M, int N, int K, int lda) {
    int b256 = (M / 256) * (N / 256);
    if ((M % 128) == 0 && (N % 256) == 0 && b256 >= 256) {
      int nbx = (M + 255) / 256, nby = N / 256;
      dim3 g(nbx * nby);
      switch (EPI) {
        case 0: g256<0><<<g, 512, 131072, stream>>>(A, B, bias, Cf, Cb, M, N, K, lda, nbx, nby); break;
        case 1: g256<1><<<g, 512, 131072, stream>>>(A, B, bias, Cf, Cb, M, N, K, lda, nbx, nby); break;
        case 2: g256<2><<<g, 512, 131072, stream>>>(A, B, bias, Cf, Cb, M, N, K, lda, nbx, nby); break;
        default: g256<3><<<g, 512, 131072, stream>>>(A, B, bias, Cf, Cb, M, N, K, lda, nbx, nby); break;
      }
    } else {
      int nbx = (M + 127) / 128, nby = N / 128;
      dim3 g(nbx * nby);
      switch (EPI) {
        case 0: gemm_bt<0><<<g, 256, 0, stream>>>(A, B, bias, Cf, Cb, M, N, K, lda, nbx, nby); break;
        case 1: gemm_bt<1><<<g, 256, 0, stream>>>(A, B, bias, Cf, Cb, M, N, K, lda, nbx, nby); break;
        case 2: gemm_bt<2><<<g, 256, 0, stream>>>(A, B, bias, Cf, Cb, M, N, K, lda, nbx, nby); break;
        default: gemm_bt<3><<<g, 256, 0, stream>>>(A, B, bias, Cf, Cb, M, N, K, lda, nbx, nby); break;
      }
    }
  };

  for (int n = 0; n < 2; ++n) {
    for (int sl = 0; sl < s; ++sl) {
      long tok0 = (long)n * 40960 + (long)sl * dcount * 1280;
      long q0g  = (long)n * 5120 + (long)sl * dgc * 320;
      const float* xg = x + tok0 * 1024;

      pool_cvt<<<Tq, 256, 0, stream>>>(xg, Xb, Qp);

      launch_gemm(1, Xb, wb_kv1, b_kv1, nullptr, Hb2, Tc, 2048, 1024, 1024);
      launch_gemm(0, Hb2, wb_k2, k_b2, nullptr, Kb, Tc, 1024, 1024, 2048);
      ln_ip<<<Tc, 256, 0, stream>>>(Kb, lnk_w, lnk_b);
      launch_gemm(0, Hb2 + 1024, wb_v2, v_b2, nullptr, Vb, Tc, 1024, 1024, 2048);
      ln_ip<<<Tc, 256, 0, stream>>>(Vb, lnv_w, lnv_b);

      launch_gemm(3, Qp, wb_q, nullptr, nullptr, QQ, Tq, 1024, 1024, 1024);
      ln_ip<<<Tq, 256, 0, stream>>>(QQ, lnq_w, lnq_b);
      launch_gemm(0, QQ, wb_in, in_b, nullptr, QHb, Tq, 1024, 1024, 1024);

      launch_gemm(0, Kb, wb_in + CC, in_b + 1024, nullptr, Xb, Tc, 1024, 1024, 1024);
      launch_gemm(0, Vb, wb_in + 2 * CC, in_b + 2048, nullptr, Hb2, Tc, 1024, 1024, 1024);

      attn_k<<<Tq, 256, 0, stream>>>(QHb, Xb, Hb2, Ob);

      launch_gemm(0, Ob, wb_out, out_b, nullptr, O2, Tq, 1024, 1024, 1024);
      launch_gemm(1, O2, wb_m1, mlp_b1, nullptr, Hm, Tq, 2048, 1024, 1024);
      launch_gemm(2, Hm, wb_m2, mlp_b2, out + q0g * 2048, nullptr, Tq, 2048, 2048, 2048);
    }
  }
}

// Round 6
// 2449.912 us; speedup vs baseline: 1.9823x; 1.0045x over previous
//
#include <hip/hip_runtime.h>

typedef __attribute__((ext_vector_type(8))) short bf16x8;
typedef __attribute__((ext_vector_type(4))) float f32x4;
typedef unsigned short u16;

// ---------- helpers ----------
__device__ inline u16 f2b(float f) {
  union { float f; unsigned u; } x; x.f = f;
  unsigned r = x.u + 0x7FFFu + ((x.u >> 16) & 1u);
  return (u16)(r >> 16);
}
__device__ inline float b2f(u16 s) {
  union { unsigned u; float f; } x; x.u = ((unsigned)s) << 16;
  return x.f;
}
__device__ inline float gelu_f(float v) {
  return 0.5f * v * (1.0f + erff(v * 0.70710678118654752f));
}
__device__ inline void gll16(const void* g, void* lds) {
  __builtin_amdgcn_global_load_lds((const __attribute__((address_space(1))) void*)g,
                                   (__attribute__((address_space(3))) void*)lds,
                                   16, 0, 0);
}

// ---------- weight convert fp32 -> bf16 ----------
__global__ __launch_bounds__(256) void cvt_w(const float* __restrict__ s,
                                             u16* __restrict__ d, int n4) {
  int i = blockIdx.x * 256 + threadIdx.x;
  if (i < n4) {
    float4 v = ((const float4*)s)[i];
    ushort4 o; o.x = f2b(v.x); o.y = f2b(v.y); o.z = f2b(v.z); o.w = f2b(v.w);
    ((ushort4*)d)[i] = o;
  }
}

__global__ __launch_bounds__(256) void cat_bias(const float* __restrict__ a,
                                                const float* __restrict__ b,
                                                float* __restrict__ o) {
  int i = blockIdx.x * 256 + threadIdx.x;
  if (i < 1024) { o[i] = a[i]; o[1024 + i] = b[i]; }
}

// ---------- fused x->bf16 convert + 2x2x2 mean pool ----------
__global__ __launch_bounds__(256) void pool_cvt(const float* __restrict__ xg,
                                                u16* __restrict__ Xb,
                                                u16* __restrict__ Qp) {
  int qr = blockIdx.x;
  int wgi = qr & 15;
  int hgi = (qr >> 4) % 20;
  int dgi = qr / 320;
  int c = threadIdx.x * 4;
  float sx = 0.f, sy = 0.f, sz = 0.f, sw = 0.f;
#pragma unroll
  for (int j = 0; j < 8; ++j) {
    int tr = ((2 * dgi + (j >> 2)) * 40 + (2 * hgi + ((j >> 1) & 1))) * 32 +
             (2 * wgi + (j & 1));
    long off = (long)tr * 1024 + c;
    float4 v = *(const float4*)&xg[off];
    ushort4 o; o.x = f2b(v.x); o.y = f2b(v.y); o.z = f2b(v.z); o.w = f2b(v.w);
    *(ushort4*)&Xb[off] = o;
    sx += v.x; sy += v.y; sz += v.z; sw += v.w;
  }
  ushort4 o;
  o.x = f2b(sx * 0.125f); o.y = f2b(sy * 0.125f);
  o.z = f2b(sz * 0.125f); o.w = f2b(sw * 0.125f);
  *(ushort4*)&Qp[(long)qr * 1024 + c] = o;
}

// ---------- in-place LayerNorm over rows of 1024 bf16 ----------
__global__ __launch_bounds__(256) void ln_ip(u16* __restrict__ X,
                                             const float* __restrict__ w,
                                             const float* __restrict__ b) {
  long row = blockIdx.x;
  int c = threadIdx.x * 4;
  ushort4 v = *(const ushort4*)&X[row * 1024 + c];
  float f0 = b2f(v.x), f1 = b2f(v.y), f2 = b2f(v.z), f3 = b2f(v.w);
  float s = f0 + f1 + f2 + f3;
  float q = f0 * f0 + f1 * f1 + f2 * f2 + f3 * f3;
#pragma unroll
  for (int off = 32; off >= 1; off >>= 1) {
    s += __shfl_xor(s, off);
    q += __shfl_xor(q, off);
  }
  __shared__ float red[8];
  int wv = threadIdx.x >> 6, ln = threadIdx.x & 63;
  if (ln == 0) { red[wv] = s; red[4 + wv] = q; }
  __syncthreads();
  s = red[0] + red[1] + red[2] + red[3];
  q = red[4] + red[5] + red[6] + red[7];
  float mean = s * (1.f / 1024.f);
  float var = q * (1.f / 1024.f) - mean * mean;
  float rs = rsqrtf(var + 1e-6f);
  float4 wv4 = *(const float4*)&w[c];
  float4 bv4 = *(const float4*)&b[c];
  ushort4 o;
  o.x = f2b((f0 - mean) * rs * wv4.x + bv4.x);
  o.y = f2b((f1 - mean) * rs * wv4.y + bv4.y);
  o.z = f2b((f2 - mean) * rs * wv4.z + bv4.z);
  o.w = f2b((f3 - mean) * rs * wv4.w + bv4.w);
  *(ushort4*)&X[row * 1024 + c] = o;
}

#define MFMA16(a, b, c) __builtin_amdgcn_mfma_f32_16x16x32_bf16((a), (b), (c), 0, 0, 0)

// ---------- 128x128 2-phase GEMM (round-2 verified) ----------
#define BK 32
template <int EPI>
__global__ __launch_bounds__(256) void gemm_bt(const u16* __restrict__ A,
                                               const u16* __restrict__ B,
                                               const float* __restrict__ bias,
                                               float* __restrict__ Cf,
                                               u16* __restrict__ Cb,
                                               int M, int N, int K, int lda,
                                               int nbx, int nby) {
  __shared__ __align__(16) u16 As0[128 * BK];
  __shared__ __align__(16) u16 Bs0[128 * BK];
  __shared__ __align__(16) u16 As1[128 * BK];
  __shared__ __align__(16) u16 Bs1[128 * BK];
  const int tid = threadIdx.x;

  int L = blockIdx.x, bx, by;
  if ((nbx & 7) == 0) {
    int xcd = L & 7, j = L >> 3, ppx = nbx >> 3;
    int pj = j / nby;
    bx = xcd * ppx + pj;
    by = j - pj * nby;
  } else {
    bx = L % nbx;
    by = L / nbx;
  }
  const int bm = bx * 128, bn = by * 128;

  const int l = tid & 63, wv = tid >> 6;
  const int wm = (wv >> 1) * 64, wn = (wv & 1) * 64;
  const int lr = l & 15, kg = l >> 4;

  const int ea = tid * 8, eb = (256 + tid) * 8;
  const int ra = ea >> 5, ca = ea & 31;
  const int rb = eb >> 5, cbn = eb & 31;
  int gra = bm + ra; if (gra > M - 1) gra = M - 1;
  int grb = bm + rb; if (grb > M - 1) grb = M - 1;
  const u16* pa0 = A + (long)gra * lda + ca;
  const u16* pa1 = A + (long)grb * lda + cbn;
  const u16* pb0 = B + (long)(bn + ra) * K + ca;
  const u16* pb1 = B + (long)(bn + rb) * K + cbn;

  f32x4 acc[4][4] = {};
  const int nt = K / BK;

#define STAGE(AS, BS, k0)                \
  do {                                   \
    gll16(pa0 + (k0), &(AS)[ea]);        \
    gll16(pb0 + (k0), &(BS)[ea]);        \
    gll16(pa1 + (k0), &(AS)[eb]);        \
    gll16(pb1 + (k0), &(BS)[eb]);        \
  } while (0)

#define COMPUTE(AS, BS)                                                       \
  do {                                                                        \
    bf16x8 af[4], bfr[4];                                                     \
    _Pragma("unroll") for (int m = 0; m < 4; ++m)                             \
        af[m] = *(const bf16x8*)&(AS)[(wm + m * 16 + lr) * BK + kg * 8];      \
    _Pragma("unroll") for (int n = 0; n < 4; ++n)                             \
        bfr[n] = *(const bf16x8*)&(BS)[(wn + n * 16 + lr) * BK + kg * 8];     \
    _Pragma("unroll") for (int m = 0; m < 4; ++m)                             \
        _Pragma("unroll") for (int n = 0; n < 4; ++n)                         \
            acc[m][n] = MFMA16(af[m], bfr[n], acc[m][n]);                     \
  } while (0)

  STAGE(As0, Bs0, 0);
  __syncthreads();
  for (int t = 0; t < nt; t += 2) {
    if (t + 1 < nt) STAGE(As1, Bs1, (t + 1) * BK);
    COMPUTE(As0, Bs0);
    __syncthreads();
    if (t + 2 < nt) STAGE(As0, Bs0, (t + 2) * BK);
    COMPUTE(As1, Bs1);
    __syncthreads();
  }
#undef STAGE
#undef COMPUTE

#pragma unroll
  for (int m = 0; m < 4; ++m) {
    int row0 = bm + wm + m * 16 + kg * 4;
#pragma unroll
    for (int n = 0; n < 4; ++n) {
      int col = bn + wn + n * 16 + lr;
      float bsv = (EPI == 3) ? 0.f : bias[col];
#pragma unroll
      for (int r = 0; r < 4; ++r) {
        int row = row0 + r;
        if (row < M) {
          float v = acc[m][n][r] + bsv;
          if (EPI == 1) v = gelu_f(v);
          if (EPI == 2) Cf[(long)row * N + col] = v;
          else Cb[(long)row * N + col] = f2b(v);
        }
      }
    }
  }
}

// ---------- 256x256 4-phase GEMM, BK=64, counted vmcnt(8), grouped ----------
// Round-3-verified geometry (staging, swizzle, epilogue); corrected waitcnt
// ledger: at phase-4, vmcnt(8) drains exactly tile t+1's 4 halves (3-7 phase
// cover each) and keeps tile t+2's 8 loads in flight.
// Group support: blocks with bm >= M1 use the second {A,B,bias,Cb,M2} set.
#define HALF 8192
template <int EPI>
__global__ __launch_bounds__(512, 2) void g256(const u16* __restrict__ A,
                                               const u16* __restrict__ B,
                                               const float* __restrict__ bias,
                                               float* __restrict__ Cf,
                                               u16* __restrict__ Cb,
                                               int M1, int N, int K, int lda,
                                               int nbx, int nby,
                                               const u16* __restrict__ A2,
                                               const u16* __restrict__ B2,
                                               const float* __restrict__ bias2,
                                               u16* __restrict__ Cb2, int M2) {
  extern __shared__ u16 lds[];
  u16* ASm = lds;
  u16* BSm = lds + 4 * HALF;
  const int tid = threadIdx.x;
  const int l = tid & 63, w = tid >> 6;
  const int wr = w >> 2, wc = w & 3;
  const int lr = l & 15, kg = l >> 4;
  const int e7 = l & 7;

  int L = blockIdx.x, bx, by;
  if ((nbx & 7) == 0) {
    int xcd = L & 7, j = L >> 3, ppx = nbx >> 3;
    int pj = j / nby;
    bx = xcd * ppx + pj;
    by = j - pj * nby;
  } else {
    bx = L % nbx;
    by = L / nbx;
  }
  int bm = bx * 256;
  const int bn = by * 256;

  int M = M1;
  if (bm >= M1) {  // group 2
    A = A2; B = B2; bias = bias2; Cb = Cb2;
    bm -= M1; M = M2;
  }

  // staging geometry: thread handles chunks c0, c1 of each 128x64 half
  const int c0 = w * 64 + l, c1 = 512 + c0;
  const int r0 = c0 >> 3, cs0 = (c0 & 7) ^ (r0 & 7);
  const int r1 = c1 >> 3, cs1 = (c1 & 7) ^ (r1 & 7);
  const u16* Ab = A + (long)bm * lda;
  const u16* Bb = B + (long)bn * K;
  int a0r0 = min(bm + r0, M - 1) - bm;
  int a0r1 = min(bm + r1, M - 1) - bm;
  int a1r0 = min(bm + 128 + r0, M - 1) - bm;
  int a1r1 = min(bm + 128 + r1, M - 1) - bm;
  const int oA00 = a0r0 * lda + cs0 * 8, oA01 = a0r1 * lda + cs1 * 8;
  const int oA10 = a1r0 * lda + cs0 * 8, oA11 = a1r1 * lda + cs1 * 8;
  const int oB00 = r0 * K + cs0 * 8, oB01 = r1 * K + cs1 * 8;
  const int oB10 = (128 + r0) * K + cs0 * 8, oB11 = (128 + r1) * K + cs1 * 8;
  const int d0 = c0 * 8, d1 = c1 * 8;

  const int sw0 = ((kg) ^ e7) * 8;
  const int sw1 = ((4 + kg) ^ e7) * 8;

  f32x4 acc[8][4] = {};
  bf16x8 af[4][2], bf[2][2][2];
  const int nt = K / 64;

#define STG_A(slot, o0_, o1_, ko) do { \
    gll16(Ab + (o0_) + (ko), ASm + (slot) * HALF + d0); \
    gll16(Ab + (o1_) + (ko), ASm + (slot) * HALF + d1); } while (0)
#define STG_B(slot, o0_, o1_, ko) do { \
    gll16(Bb + (o0_) + (ko), BSm + (slot) * HALF + d0); \
    gll16(Bb + (o1_) + (ko), BSm + (slot) * HALF + d1); } while (0)

  // prologue: tile0 full (slots parity 0) + tile1 Ah0/Bh0/Bh1 (parity 1)
  STG_A(0, oA00, oA01, 0); STG_A(1, oA10, oA11, 0);
  STG_B(0, oB00, oB01, 0); STG_B(1, oB10, oB11, 0);
  STG_A(2, oA00, oA01, 64); STG_B(2, oB00, oB01, 64); STG_B(3, oB10, oB11, 64);
  asm volatile("s_waitcnt vmcnt(6)" ::: "memory");
  __builtin_amdgcn_s_barrier();

  const int rbA = wr * 64 + lr;
  const int rbB = (wc & 1) * 64 + lr;

  for (int t = 0; t < nt; ++t) {
    const int p = t & 1, qp = p ^ 1;
    const int kn1 = (t + 1 < nt ? t + 1 : nt - 1) * 64;
    const int kn2 = (t + 2 < nt ? t + 2 : nt - 1) * 64;
    const u16* sa0 = ASm + (p * 2 + 0) * HALF;
    const u16* sa1 = ASm + (p * 2 + 1) * HALF;
    const u16* sb = BSm + (p * 2 + (wc >> 1)) * HALF;

    // ---- phase 1: quadrant (mh0,nh0); stage A-h1(t+1)
#pragma unroll
    for (int mq = 0; mq < 4; ++mq) {
      af[mq][0] = *(const bf16x8*)&sa0[(rbA + mq * 16) * 64 + sw0];
      af[mq][1] = *(const bf16x8*)&sa0[(rbA + mq * 16) * 64 + sw1];
    }
#pragma unroll
    for (int nn = 0; nn < 2; ++nn) {
      bf[0][nn][0] = *(const bf16x8*)&sb[(rbB + nn * 16) * 64 + sw0];
      bf[0][nn][1] = *(const bf16x8*)&sb[(rbB + nn * 16) * 64 + sw1];
    }
    STG_A(qp * 2 + 1, oA10, oA11, kn1);
    __builtin_amdgcn_s_barrier();
    __builtin_amdgcn_s_setprio(1);
#pragma unroll
    for (int mq = 0; mq < 4; ++mq)
#pragma unroll
      for (int nn = 0; nn < 2; ++nn) {
        acc[mq][nn] = MFMA16(af[mq][0], bf[0][nn][0], acc[mq][nn]);
        acc[mq][nn] = MFMA16(af[mq][1], bf[0][nn][1], acc[mq][nn]);
      }
    __builtin_amdgcn_s_setprio(0);
    __builtin_amdgcn_s_barrier();

    // ---- phase 2: (mh0,nh1); stage A-h0(t+2)
#pragma unroll
    for (int nn = 0; nn < 2; ++nn) {
      bf[1][nn][0] = *(const bf16x8*)&sb[(rbB + (2 + nn) * 16) * 64 + sw0];
      bf[1][nn][1] = *(const bf16x8*)&sb[(rbB + (2 + nn) * 16) * 64 + sw1];
    }
    STG_A(p * 2 + 0, oA00, oA01, kn2);
    __builtin_amdgcn_s_barrier();
    __builtin_amdgcn_s_setprio(1);
#pragma unroll
    for (int mq = 0; mq < 4; ++mq)
#pragma unroll
      for (int nn = 0; nn < 2; ++nn) {
        acc[mq][2 + nn] = MFMA16(af[mq][0], bf[1][nn][0], acc[mq][2 + nn]);
        acc[mq][2 + nn] = MFMA16(af[mq][1], bf[1][nn][1], acc[mq][2 + nn]);
      }
    __builtin_amdgcn_s_setprio(0);
    __builtin_amdgcn_s_barrier();

    // ---- phase 3: (mh1,nh0); stage B-h0(t+2)
#pragma unroll
    for (int mq = 0; mq < 4; ++mq) {
      af[mq][0] = *(const bf16x8*)&sa1[(rbA + mq * 16) * 64 + sw0];
      af[mq][1] = *(const bf16x8*)&sa1[(rbA + mq * 16) * 64 + sw1];
    }
    STG_B(p * 2 + 0, oB00, oB01, kn2);
    __builtin_amdgcn_s_barrier();
    __builtin_amdgcn_s_setprio(1);
#pragma unroll
    for (int mq = 0; mq < 4; ++mq)
#pragma unroll
      for (int nn = 0; nn < 2; ++nn) {
        acc[4 + mq][nn] = MFMA16(af[mq][0], bf[0][nn][0], acc[4 + mq][nn]);
        acc[4 + mq][nn] = MFMA16(af[mq][1], bf[0][nn][1], acc[4 + mq][nn]);
      }
    __builtin_amdgcn_s_setprio(0);
    __builtin_amdgcn_s_barrier();

    // ---- phase 4: (mh1,nh1); stage B-h1(t+2); counted vmcnt(8)
    STG_B(p * 2 + 1, oB10, oB11, kn2);
    asm volatile("s_waitcnt vmcnt(8)" ::: "memory");
    __builtin_amdgcn_s_barrier();
    __builtin_amdgcn_s_setprio(1);
#pragma unroll
    for (int mq = 0; mq < 4; ++mq)
#pragma unroll
      for (int nn = 0; nn < 2; ++nn) {
        acc[4 + mq][2 + nn] = MFMA16(af[mq][0], bf[1][nn][0], acc[4 + mq][2 + nn]);
        acc[4 + mq][2 + nn] = MFMA16(af[mq][1], bf[1][nn][1], acc[4 + mq][2 + nn]);
      }
    __builtin_amdgcn_s_setprio(0);
    __builtin_amdgcn_s_barrier();
  }
  asm volatile("s_waitcnt vmcnt(0)" ::: "memory");
#undef STG_A
#undef STG_B

  // ---- epilogue ----
#pragma unroll
  for (int m = 0; m < 8; ++m) {
    int row = bm + (m >> 2) * 128 + wr * 64 + (m & 3) * 16 + kg * 4;
#pragma unroll
    for (int n = 0; n < 4; ++n) {
      int col = bn + wc * 64 + n * 16 + lr;
      float bsv = (EPI == 3) ? 0.f : bias[col];
#pragma unroll
      for (int r = 0; r < 4; ++r) {
        if (row + r < M) {
          float v = acc[m][n][r] + bsv;
          if (EPI == 1) v = gelu_f(v);
          if (EPI == 2) Cf[(long)(row + r) * N + col] = v;
          else Cb[(long)(row + r) * N + col] = f2b(v);
        }
      }
    }
  }
}

// ---------- 8-key local attention ----------
__global__ __launch_bounds__(256) void attn_k(const u16* __restrict__ QH,
                                              const u16* __restrict__ KH,
                                              const u16* __restrict__ VH,
                                              u16* __restrict__ O) {
  int qr = blockIdx.x;
  int wgi = qr & 15;
  int hgi = (qr >> 4) % 20;
  int dgi = qr / 320;
  int c0 = (threadIdx.x >> 5) * 128 + (threadIdx.x & 31) * 4;
  ushort4 qv = *(const ushort4*)&QH[(long)qr * 1024 + c0];
  float q0 = b2f(qv.x), q1 = b2f(qv.y), q2 = b2f(qv.z), q3 = b2f(qv.w);
  long trs[8];
  float sc[8];
#pragma unroll
  for (int j = 0; j < 8; ++j) {
    int tr = ((2 * dgi + (j >> 2)) * 40 + (2 * hgi + ((j >> 1) & 1))) * 32 +
             (2 * wgi + (j & 1));
    trs[j] = (long)tr * 1024 + c0;
    ushort4 kv = *(const ushort4*)&KH[trs[j]];
    float p = q0 * b2f(kv.x) + q1 * b2f(kv.y) + q2 * b2f(kv.z) + q3 * b2f(kv.w);
    p += __shfl_xor(p, 16); p += __shfl_xor(p, 8); p += __shfl_xor(p, 4);
    p += __shfl_xor(p, 2);  p += __shfl_xor(p, 1);
    sc[j] = p * 0.088388347648318447f;  // 1/sqrt(128)
  }
  float mx = sc[0];
#pragma unroll
  for (int j = 1; j < 8; ++j) mx = fmaxf(mx, sc[j]);
  float ssum = 0.f;
#pragma unroll
  for (int j = 0; j < 8; ++j) { sc[j] = expf(sc[j] - mx); ssum += sc[j]; }
  float inv = 1.0f / ssum;
  float o0 = 0, o1 = 0, o2 = 0, o3 = 0;
#pragma unroll
  for (int j = 0; j < 8; ++j) {
    ushort4 vv = *(const ushort4*)&VH[trs[j]];
    float p = sc[j] * inv;
    o0 += p * b2f(vv.x); o1 += p * b2f(vv.y);
    o2 += p * b2f(vv.z); o3 += p * b2f(vv.w);
  }
  ushort4 ov; ov.x = f2b(o0); ov.y = f2b(o1); ov.z = f2b(o2); ov.w = f2b(o3);
  *(ushort4*)&O[(long)qr * 1024 + c0] = ov;
}

// ---------- host ----------
extern "C" void kernel_launch(void* const* d_in, const int* in_sizes, int n_in,
                              void* d_out, int out_size, void* d_ws,
                              size_t ws_size, hipStream_t stream) {
  const float* x      = (const float*)d_in[0];
  const float* q_w    = (const float*)d_in[1];
  const float* k_w1   = (const float*)d_in[2];
  const float* k_b1   = (const float*)d_in[3];
  const float* k_w2   = (const float*)d_in[4];
  const float* k_b2   = (const float*)d_in[5];
  const float* v_w1   = (const float*)d_in[6];
  const float* v_b1   = (const float*)d_in[7];
  const float* v_w2   = (const float*)d_in[8];
  const float* v_b2   = (const float*)d_in[9];
  const float* lnq_w  = (const float*)d_in[10];
  const float* lnq_b  = (const float*)d_in[11];
  const float* lnk_w  = (const float*)d_in[12];
  const float* lnk_b  = (const float*)d_in[13];
  const float* lnv_w  = (const float*)d_in[14];
  const float* lnv_b  = (const float*)d_in[15];
  const float* in_w   = (const float*)d_in[16];
  const float* in_b   = (const float*)d_in[17];
  const float* out_w  = (const float*)d_in[18];
  const float* out_b  = (const float*)d_in[19];
  const float* mlp_w1 = (const float*)d_in[20];
  const float* mlp_b1 = (const float*)d_in[21];
  const float* mlp_w2 = (const float*)d_in[22];
  const float* mlp_b2 = (const float*)d_in[23];
  float* out = (float*)d_out;

  hipFuncSetAttribute((const void*)g256<0>, hipFuncAttributeMaxDynamicSharedMemorySize, 131072);
  hipFuncSetAttribute((const void*)g256<1>, hipFuncAttributeMaxDynamicSharedMemorySize, 131072);
  hipFuncSetAttribute((const void*)g256<2>, hipFuncAttributeMaxDynamicSharedMemorySize, 131072);
  hipFuncSetAttribute((const void*)g256<3>, hipFuncAttributeMaxDynamicSharedMemorySize, 131072);

  char* base = (char*)d_ws;
  size_t off = 0;
  auto alloc_us = [&](size_t elems) -> u16* {
    u16* r = (u16*)(base + off);
    off += ((elems * 2 + 255) & ~(size_t)255);
    return r;
  };
  const size_t CC = 1024 * 1024;
  u16* wb_q   = alloc_us(CC);
  u16* wb_kv1 = alloc_us(2 * CC);
  u16* wb_k2  = alloc_us(CC);
  u16* wb_v2  = alloc_us(CC);
  u16* wb_in  = alloc_us(3 * CC);
  u16* wb_out = alloc_us(CC);
  u16* wb_m1  = alloc_us(2 * CC);
  u16* wb_m2  = alloc_us(4 * CC);
  float* b_kv1 = (float*)(base + off); off += 2048 * 4;

  auto cvt = [&](const float* s, u16* d, size_t n) {
    int n4 = (int)(n / 4);
    cvt_w<<<(n4 + 255) / 256, 256, 0, stream>>>(s, d, n4);
  };
  cvt(q_w, wb_q, CC);
  cvt(k_w1, wb_kv1, CC);        cvt(v_w1, wb_kv1 + CC, CC);
  cvt(k_w2, wb_k2, CC);         cvt(v_w2, wb_v2, CC);
  cvt(in_w, wb_in, 3 * CC);     cvt(out_w, wb_out, CC);
  cvt(mlp_w1, wb_m1, 2 * CC);   cvt(mlp_w2, wb_m2, 4 * CC);
  cat_bias<<<4, 256, 0, stream>>>(k_b1, v_b1, b_kv1);

  int s = 16;
  for (int cand = 1; cand <= 16; cand <<= 1) {
    size_t Tc_ = 40960ull / cand;
    size_t need = off + Tc_ * 11520ull + (1ull << 20);
    if (need <= ws_size) { s = cand; break; }
  }
  const int dcount = 32 / s;
  const int dgc = dcount / 2;
  const int Tc = dcount * 1280;
  const int Tq = dgc * 320;

  u16* Xb  = alloc_us((size_t)Tc * 1024);
  u16* Hb2 = alloc_us((size_t)Tc * 2048);
  u16* Kb  = alloc_us((size_t)Tc * 1024);
  u16* Vb  = alloc_us((size_t)Tc * 1024);
  u16* Qp  = alloc_us((size_t)Tq * 1024);
  u16* QQ  = alloc_us((size_t)Tq * 1024);
  u16* QHb = alloc_us((size_t)Tq * 1024);
  u16* Ob  = alloc_us((size_t)Tq * 1024);
  u16* O2  = alloc_us((size_t)Tq * 1024);
  u16* Hm  = Kb;

  // grouped g256 launch: [A1,M1]+[A2,M2] stacked on the M axis
  auto launch_g256_grp = [&](int EPI, const u16* A1, const u16* B1,
                             const float* bias1, float* Cf, u16* Cb1, int M1,
                             const u16* A2, const u16* B2, const float* bias2,
                             u16* Cb2, int M2, int N, int K, int lda) {
    int nbx = (M1 + M2) / 256, nby = N / 256;
    dim3 g(nbx * nby);
    switch (EPI) {
      case 0: g256<0><<<g, 512, 131072, stream>>>(A1, B1, bias1, Cf, Cb1, M1, N, K, lda, nbx, nby, A2, B2, bias2, Cb2, M2); break;
      case 1: g256<1><<<g, 512, 131072, stream>>>(A1, B1, bias1, Cf, Cb1, M1, N, K, lda, nbx, nby, A2, B2, bias2, Cb2, M2); break;
      case 2: g256<2><<<g, 512, 131072, stream>>>(A1, B1, bias1, Cf, Cb1, M1, N, K, lda, nbx, nby, A2, B2, bias2, Cb2, M2); break;
      default: g256<3><<<g, 512, 131072, stream>>>(A1, B1, bias1, Cf, Cb1, M1, N, K, lda, nbx, nby, A2, B2, bias2, Cb2, M2); break;
    }
  };

  auto launch_gemm = [&](int EPI, const u16* A, const u16* B, const float* bias,
                         float* Cf, u16* Cb, int M, int N, int K, int lda) {
    int b256 = (M / 256) * (N / 256);
    if ((M % 256) == 0 && (N % 256) == 0 && b256 >= 256) {
      launch_g256_grp(EPI, A, B, bias, Cf, Cb, M, nullptr, nullptr, nullptr,
                      nullptr, 0, N, K, lda);
    } else {
      int nbx = (M + 127) / 128, nby = N / 128;
      dim3 g(nbx * nby);
      switch (EPI) {
        case 0: gemm_bt<0><<<g, 256, 0, stream>>>(A, B, bias, Cf, Cb, M, N, K, lda, nbx, nby); break;
        case 1: gemm_bt<1><<<g, 256, 0, stream>>>(A, B, bias, Cf, Cb, M, N, K, lda, nbx, nby); break;
        case 2: gemm_bt<2><<<g, 256, 0, stream>>>(A, B, bias, Cf, Cb, M, N, K, lda, nbx, nby); break;
        default: gemm_bt<3><<<g, 256, 0, stream>>>(A, B, bias, Cf, Cb, M, N, K, lda, nbx, nby); break;
      }
    }
  };

  for (int n = 0; n < 2; ++n) {
    for (int sl = 0; sl < s; ++sl) {
      long tok0 = (long)n * 40960 + (long)sl * dcount * 1280;
      long q0g  = (long)n * 5120 + (long)sl * dgc * 320;
      const float* xg = x + tok0 * 1024;

      pool_cvt<<<Tq, 256, 0, stream>>>(xg, Xb, Qp);

      // fused k1+v1 -> gelu -> Hb2 (Tc x 2048)
      launch_gemm(1, Xb, wb_kv1, b_kv1, nullptr, Hb2, Tc, 2048, 1024, 1024);
      // grouped k2 + v2 (one 0-tail dispatch)
      launch_g256_grp(0, Hb2, wb_k2, k_b2, nullptr, Kb, Tc,
                      Hb2 + 1024, wb_v2, v_b2, Vb, Tc, 1024, 1024, 2048);
      ln_ip<<<Tc, 256, 0, stream>>>(Kb, lnk_w, lnk_b);
      ln_ip<<<Tc, 256, 0, stream>>>(Vb, lnv_w, lnv_b);

      // q path
      launch_gemm(3, Qp, wb_q, nullptr, nullptr, QQ, Tq, 1024, 1024, 1024);
      ln_ip<<<Tq, 256, 0, stream>>>(QQ, lnq_w, lnq_b);
      launch_gemm(0, QQ, wb_in, in_b, nullptr, QHb, Tq, 1024, 1024, 1024);

      // grouped kh + vh: kh -> Xb, vh -> Hb2
      launch_g256_grp(0, Kb, wb_in + CC, in_b + 1024, nullptr, Xb, Tc,
                      Vb, wb_in + 2 * CC, in_b + 2048, Hb2, Tc, 1024, 1024, 1024);

      attn_k<<<Tq, 256, 0, stream>>>(QHb, Xb, Hb2, Ob);

      launch_gemm(0, Ob, wb_out, out_b, nullptr, O2, Tq, 1024, 1024, 1024);
      launch_gemm(1, O2, wb_m1, mlp_b1, nullptr, Hm, Tq, 2048, 1024, 1024);
      launch_gemm(2, Hm, wb_m2, mlp_b2, out + q0g * 2048, nullptr, Tq, 2048, 2048, 2048);
    }
  }
}

// Round 8
// 2309.794 us; speedup vs baseline: 2.1025x; 1.0607x over previous
//
#include <hip/hip_runtime.h>

typedef __attribute__((ext_vector_type(8))) short bf16x8;
typedef __attribute__((ext_vector_type(4))) float f32x4;
typedef unsigned short u16;

// ---------- helpers ----------
__device__ inline u16 f2b(float f) {
  union { float f; unsigned u; } x; x.f = f;
  unsigned r = x.u + 0x7FFFu + ((x.u >> 16) & 1u);
  return (u16)(r >> 16);
}
__device__ inline float b2f(u16 s) {
  union { unsigned u; float f; } x; x.u = ((unsigned)s) << 16;
  return x.f;
}
__device__ inline float gelu_f(float v) {
  return 0.5f * v * (1.0f + erff(v * 0.70710678118654752f));
}
__device__ inline void gll16(const void* g, void* lds) {
  __builtin_amdgcn_global_load_lds((const __attribute__((address_space(1))) void*)g,
                                   (__attribute__((address_space(3))) void*)lds,
                                   16, 0, 0);
}

// ---------- weight convert fp32 -> bf16 ----------
__global__ __launch_bounds__(256) void cvt_w(const float* __restrict__ s,
                                             u16* __restrict__ d, int n4) {
  int i = blockIdx.x * 256 + threadIdx.x;
  if (i < n4) {
    float4 v = ((const float4*)s)[i];
    ushort4 o; o.x = f2b(v.x); o.y = f2b(v.y); o.z = f2b(v.z); o.w = f2b(v.w);
    ((ushort4*)d)[i] = o;
  }
}

__global__ __launch_bounds__(256) void cat_bias(const float* __restrict__ a,
                                                const float* __restrict__ b,
                                                float* __restrict__ o) {
  int i = blockIdx.x * 256 + threadIdx.x;
  if (i < 1024) { o[i] = a[i]; o[1024 + i] = b[i]; }
}

// ---------- fused x->bf16 convert + 2x2x2 mean pool ----------
__global__ __launch_bounds__(256) void pool_cvt(const float* __restrict__ xg,
                                                u16* __restrict__ Xb,
                                                u16* __restrict__ Qp) {
  int qr = blockIdx.x;
  int wgi = qr & 15;
  int hgi = (qr >> 4) % 20;
  int dgi = qr / 320;
  int c = threadIdx.x * 4;
  float sx = 0.f, sy = 0.f, sz = 0.f, sw = 0.f;
#pragma unroll
  for (int j = 0; j < 8; ++j) {
    int tr = ((2 * dgi + (j >> 2)) * 40 + (2 * hgi + ((j >> 1) & 1))) * 32 +
             (2 * wgi + (j & 1));
    long off = (long)tr * 1024 + c;
    float4 v = *(const float4*)&xg[off];
    ushort4 o; o.x = f2b(v.x); o.y = f2b(v.y); o.z = f2b(v.z); o.w = f2b(v.w);
    *(ushort4*)&Xb[off] = o;
    sx += v.x; sy += v.y; sz += v.z; sw += v.w;
  }
  ushort4 o;
  o.x = f2b(sx * 0.125f); o.y = f2b(sy * 0.125f);
  o.z = f2b(sz * 0.125f); o.w = f2b(sw * 0.125f);
  *(ushort4*)&Qp[(long)qr * 1024 + c] = o;
}

// ---------- in-place LayerNorm (single buffer) ----------
__global__ __launch_bounds__(256) void ln_ip(u16* __restrict__ X,
                                             const float* __restrict__ w,
                                             const float* __restrict__ b) {
  long row = blockIdx.x;
  int c = threadIdx.x * 4;
  ushort4 v = *(const ushort4*)&X[row * 1024 + c];
  float f0 = b2f(v.x), f1 = b2f(v.y), f2 = b2f(v.z), f3 = b2f(v.w);
  float s = f0 + f1 + f2 + f3;
  float q = f0 * f0 + f1 * f1 + f2 * f2 + f3 * f3;
#pragma unroll
  for (int off = 32; off >= 1; off >>= 1) {
    s += __shfl_xor(s, off);
    q += __shfl_xor(q, off);
  }
  __shared__ float red[8];
  int wv = threadIdx.x >> 6, ln = threadIdx.x & 63;
  if (ln == 0) { red[wv] = s; red[4 + wv] = q; }
  __syncthreads();
  s = red[0] + red[1] + red[2] + red[3];
  q = red[4] + red[5] + red[6] + red[7];
  float mean = s * (1.f / 1024.f);
  float var = q * (1.f / 1024.f) - mean * mean;
  float rs = rsqrtf(var + 1e-6f);
  float4 wv4 = *(const float4*)&w[c];
  float4 bv4 = *(const float4*)&b[c];
  ushort4 o;
  o.x = f2b((f0 - mean) * rs * wv4.x + bv4.x);
  o.y = f2b((f1 - mean) * rs * wv4.y + bv4.y);
  o.z = f2b((f2 - mean) * rs * wv4.z + bv4.z);
  o.w = f2b((f3 - mean) * rs * wv4.w + bv4.w);
  *(ushort4*)&X[row * 1024 + c] = o;
}

// ---------- fused dual-buffer LayerNorm (K and V in one dispatch) ----------
__global__ __launch_bounds__(256) void ln2_ip(u16* X1, const float* w1,
                                              const float* b1, u16* X2,
                                              const float* w2, const float* b2,
                                              long rows1) {
  long row = blockIdx.x;
  u16* X = X1; const float* w = w1; const float* b = b1;
  if (row >= rows1) { X = X2; w = w2; b = b2; row -= rows1; }
  int c = threadIdx.x * 4;
  ushort4 v = *(const ushort4*)&X[row * 1024 + c];
  float f0 = b2f(v.x), f1 = b2f(v.y), f2 = b2f(v.z), f3 = b2f(v.w);
  float s = f0 + f1 + f2 + f3;
  float q = f0 * f0 + f1 * f1 + f2 * f2 + f3 * f3;
#pragma unroll
  for (int off = 32; off >= 1; off >>= 1) {
    s += __shfl_xor(s, off);
    q += __shfl_xor(q, off);
  }
  __shared__ float red[8];
  int wv = threadIdx.x >> 6, ln = threadIdx.x & 63;
  if (ln == 0) { red[wv] = s; red[4 + wv] = q; }
  __syncthreads();
  s = red[0] + red[1] + red[2] + red[3];
  q = red[4] + red[5] + red[6] + red[7];
  float mean = s * (1.f / 1024.f);
  float var = q * (1.f / 1024.f) - mean * mean;
  float rs = rsqrtf(var + 1e-6f);
  float4 wv4 = *(const float4*)&w[c];
  float4 bv4 = *(const float4*)&b[c];
  ushort4 o;
  o.x = f2b((f0 - mean) * rs * wv4.x + bv4.x);
  o.y = f2b((f1 - mean) * rs * wv4.y + bv4.y);
  o.z = f2b((f2 - mean) * rs * wv4.z + bv4.z);
  o.w = f2b((f3 - mean) * rs * wv4.w + bv4.w);
  *(ushort4*)&X[row * 1024 + c] = o;
}

#define MFMA16(a, b, c) __builtin_amdgcn_mfma_f32_16x16x32_bf16((a), (b), (c), 0, 0, 0)

// ---------- 128x128 2-phase GEMM (round-2 verified core) + 3-way M-group ----
// C[M,N] = A[M,K(lda)] @ B[N,K]^T (+bias, epilogue)
// EPI: 0 bias->bf16 ; 1 bias+gelu->bf16 ; 2 bias->fp32 ; 3 nobias->bf16
// Blocks with bm >= M1 (resp. M1+M2) switch to the 2nd (3rd) operand set —
// pointer-switch mechanism correctness-verified in rounds 5/6.
#define BK 32
template <int EPI>
__global__ __launch_bounds__(256) void gemm_bt(const u16* A, const u16* B,
                                               const float* bias,
                                               float* __restrict__ Cf, u16* Cb,
                                               int M1, int N, int K, int lda,
                                               int nbx, int nby,
                                               const u16* A2, const u16* B2,
                                               const float* bias2, u16* Cb2, int M2,
                                               const u16* A3, const u16* B3,
                                               const float* bias3, u16* Cb3, int M3) {
  __shared__ __align__(16) u16 As0[128 * BK];
  __shared__ __align__(16) u16 Bs0[128 * BK];
  __shared__ __align__(16) u16 As1[128 * BK];
  __shared__ __align__(16) u16 Bs1[128 * BK];
  const int tid = threadIdx.x;

  int L = blockIdx.x, bx, by;
  if ((nbx & 7) == 0) {
    int xcd = L & 7, j = L >> 3, ppx = nbx >> 3;
    int pj = j / nby;
    bx = xcd * ppx + pj;
    by = j - pj * nby;
  } else {
    bx = L % nbx;
    by = L / nbx;
  }
  int bm = bx * 128;
  const int bn = by * 128;

  int M = M1;
  if (bm >= M1) {
    if (bm < M1 + M2) { A = A2; B = B2; bias = bias2; Cb = Cb2; bm -= M1; M = M2; }
    else { A = A3; B = B3; bias = bias3; Cb = Cb3; bm -= (M1 + M2); M = M3; }
  }

  const int l = tid & 63, wv = tid >> 6;
  const int wm = (wv >> 1) * 64, wn = (wv & 1) * 64;
  const int lr = l & 15, kg = l >> 4;

  const int ea = tid * 8, eb = (256 + tid) * 8;
  const int ra = ea >> 5, ca = ea & 31;
  const int rb = eb >> 5, cbn = eb & 31;
  int gra = bm + ra; if (gra > M - 1) gra = M - 1;
  int grb = bm + rb; if (grb > M - 1) grb = M - 1;
  const u16* pa0 = A + (long)gra * lda + ca;
  const u16* pa1 = A + (long)grb * lda + cbn;
  const u16* pb0 = B + (long)(bn + ra) * K + ca;
  const u16* pb1 = B + (long)(bn + rb) * K + cbn;

  f32x4 acc[4][4] = {};
  const int nt = K / BK;

#define STAGE(AS, BS, k0)                \
  do {                                   \
    gll16(pa0 + (k0), &(AS)[ea]);        \
    gll16(pb0 + (k0), &(BS)[ea]);        \
    gll16(pa1 + (k0), &(AS)[eb]);        \
    gll16(pb1 + (k0), &(BS)[eb]);        \
  } while (0)

#define COMPUTE(AS, BS)                                                       \
  do {                                                                        \
    bf16x8 af[4], bfr[4];                                                     \
    _Pragma("unroll") for (int m = 0; m < 4; ++m)                             \
        af[m] = *(const bf16x8*)&(AS)[(wm + m * 16 + lr) * BK + kg * 8];      \
    _Pragma("unroll") for (int n = 0; n < 4; ++n)                             \
        bfr[n] = *(const bf16x8*)&(BS)[(wn + n * 16 + lr) * BK + kg * 8];     \
    _Pragma("unroll") for (int m = 0; m < 4; ++m)                             \
        _Pragma("unroll") for (int n = 0; n < 4; ++n)                         \
            acc[m][n] = MFMA16(af[m], bfr[n], acc[m][n]);                     \
  } while (0)

  STAGE(As0, Bs0, 0);
  __syncthreads();
  for (int t = 0; t < nt; t += 2) {
    if (t + 1 < nt) STAGE(As1, Bs1, (t + 1) * BK);
    COMPUTE(As0, Bs0);
    __syncthreads();
    if (t + 2 < nt) STAGE(As0, Bs0, (t + 2) * BK);
    COMPUTE(As1, Bs1);
    __syncthreads();
  }
#undef STAGE
#undef COMPUTE

#pragma unroll
  for (int m = 0; m < 4; ++m) {
    int row0 = bm + wm + m * 16 + kg * 4;
#pragma unroll
    for (int n = 0; n < 4; ++n) {
      int col = bn + wn + n * 16 + lr;
      float bsv = (EPI == 3) ? 0.f : bias[col];
#pragma unroll
      for (int r = 0; r < 4; ++r) {
        int row = row0 + r;
        if (row < M) {
          float v = acc[m][n][r] + bsv;
          if (EPI == 1) v = gelu_f(v);
          if (EPI == 2) Cf[(long)row * N + col] = v;
          else Cb[(long)row * N + col] = f2b(v);
        }
      }
    }
  }
}

// ---------- 8-key local attention ----------
__global__ __launch_bounds__(256) void attn_k(const u16* __restrict__ QH,
                                              const u16* __restrict__ KH,
                                              const u16* __restrict__ VH,
                                              u16* __restrict__ O) {
  int qr = blockIdx.x;
  int wgi = qr & 15;
  int hgi = (qr >> 4) % 20;
  int dgi = qr / 320;
  int c0 = (threadIdx.x >> 5) * 128 + (threadIdx.x & 31) * 4;
  ushort4 qv = *(const ushort4*)&QH[(long)qr * 1024 + c0];
  float q0 = b2f(qv.x), q1 = b2f(qv.y), q2 = b2f(qv.z), q3 = b2f(qv.w);
  long trs[8];
  float sc[8];
#pragma unroll
  for (int j = 0; j < 8; ++j) {
    int tr = ((2 * dgi + (j >> 2)) * 40 + (2 * hgi + ((j >> 1) & 1))) * 32 +
             (2 * wgi + (j & 1));
    trs[j] = (long)tr * 1024 + c0;
    ushort4 kv = *(const ushort4*)&KH[trs[j]];
    float p = q0 * b2f(kv.x) + q1 * b2f(kv.y) + q2 * b2f(kv.z) + q3 * b2f(kv.w);
    p += __shfl_xor(p, 16); p += __shfl_xor(p, 8); p += __shfl_xor(p, 4);
    p += __shfl_xor(p, 2);  p += __shfl_xor(p, 1);
    sc[j] = p * 0.088388347648318447f;  // 1/sqrt(128)
  }
  float mx = sc[0];
#pragma unroll
  for (int j = 1; j < 8; ++j) mx = fmaxf(mx, sc[j]);
  float ssum = 0.f;
#pragma unroll
  for (int j = 0; j < 8; ++j) { sc[j] = expf(sc[j] - mx); ssum += sc[j]; }
  float inv = 1.0f / ssum;
  float o0 = 0, o1 = 0, o2 = 0, o3 = 0;
#pragma unroll
  for (int j = 0; j < 8; ++j) {
    ushort4 vv = *(const ushort4*)&VH[trs[j]];
    float p = sc[j] * inv;
    o0 += p * b2f(vv.x); o1 += p * b2f(vv.y);
    o2 += p * b2f(vv.z); o3 += p * b2f(vv.w);
  }
  ushort4 ov; ov.x = f2b(o0); ov.y = f2b(o1); ov.z = f2b(o2); ov.w = f2b(o3);
  *(ushort4*)&O[(long)qr * 1024 + c0] = ov;
}

// ---------- host ----------
extern "C" void kernel_launch(void* const* d_in, const int* in_sizes, int n_in,
                              void* d_out, int out_size, void* d_ws,
                              size_t ws_size, hipStream_t stream) {
  const float* x      = (const float*)d_in[0];
  const float* q_w    = (const float*)d_in[1];
  const float* k_w1   = (const float*)d_in[2];
  const float* k_b1   = (const float*)d_in[3];
  const float* k_w2   = (const float*)d_in[4];
  const float* k_b2   = (const float*)d_in[5];
  const float* v_w1   = (const float*)d_in[6];
  const float* v_b1   = (const float*)d_in[7];
  const float* v_w2   = (const float*)d_in[8];
  const float* v_b2   = (const float*)d_in[9];
  const float* lnq_w  = (const float*)d_in[10];
  const float* lnq_b  = (const float*)d_in[11];
  const float* lnk_w  = (const float*)d_in[12];
  const float* lnk_b  = (const float*)d_in[13];
  const float* lnv_w  = (const float*)d_in[14];
  const float* lnv_b  = (const float*)d_in[15];
  const float* in_w   = (const float*)d_in[16];
  const float* in_b   = (const float*)d_in[17];
  const float* out_w  = (const float*)d_in[18];
  const float* out_b  = (const float*)d_in[19];
  const float* mlp_w1 = (const float*)d_in[20];
  const float* mlp_b1 = (const float*)d_in[21];
  const float* mlp_w2 = (const float*)d_in[22];
  const float* mlp_b2 = (const float*)d_in[23];
  float* out = (float*)d_out;

  char* base = (char*)d_ws;
  size_t off = 0;
  auto alloc_us = [&](size_t elems) -> u16* {
    u16* r = (u16*)(base + off);
    off += ((elems * 2 + 255) & ~(size_t)255);
    return r;
  };
  const size_t CC = 1024 * 1024;
  u16* wb_q   = alloc_us(CC);
  u16* wb_kv1 = alloc_us(2 * CC);
  u16* wb_k2  = alloc_us(CC);
  u16* wb_v2  = alloc_us(CC);
  u16* wb_in  = alloc_us(3 * CC);
  u16* wb_out = alloc_us(CC);
  u16* wb_m1  = alloc_us(2 * CC);
  u16* wb_m2  = alloc_us(4 * CC);
  float* b_kv1 = (float*)(base + off); off += 2048 * 4;

  auto cvt = [&](const float* s, u16* d, size_t n) {
    int n4 = (int)(n / 4);
    cvt_w<<<(n4 + 255) / 256, 256, 0, stream>>>(s, d, n4);
  };
  cvt(q_w, wb_q, CC);
  cvt(k_w1, wb_kv1, CC);        cvt(v_w1, wb_kv1 + CC, CC);
  cvt(k_w2, wb_k2, CC);         cvt(v_w2, wb_v2, CC);
  cvt(in_w, wb_in, 3 * CC);     cvt(out_w, wb_out, CC);
  cvt(mlp_w1, wb_m1, 2 * CC);   cvt(mlp_w2, wb_m2, 4 * CC);
  cat_bias<<<4, 256, 0, stream>>>(k_b1, v_b1, b_kv1);

  // Flat token space: both batches contiguous; 32 dg-planes of 2560 tokens.
  // Pick largest chunk (in dg-planes) that fits the workspace.
  int dgc = 1;
  for (int cand = 32; cand >= 1; cand >>= 1) {
    size_t Tc_ = (size_t)cand * 2560;
    if (off + Tc_ * 11520ull + (1ull << 20) <= ws_size) { dgc = cand; break; }
  }
  const int Tc = dgc * 2560;   // tokens per chunk
  const int Tq = dgc * 320;    // queries per chunk

  u16* Xb  = alloc_us((size_t)Tc * 1024);
  u16* Hb2 = alloc_us((size_t)Tc * 2048);
  u16* Kb  = alloc_us((size_t)Tc * 1024);
  u16* Vb  = alloc_us((size_t)Tc * 1024);
  u16* Qp  = alloc_us((size_t)Tq * 1024);
  u16* QQ  = alloc_us((size_t)Tq * 1024);
  u16* QHb = alloc_us((size_t)Tq * 1024);
  u16* Ob  = alloc_us((size_t)Tq * 1024);
  u16* O2  = alloc_us((size_t)Tq * 1024);
  u16* Hm  = Kb;  // final-MLP hidden reuses Kb (Tq*2048 <= Tc*1024)

  // generic grouped launcher (up to 3 M-stacked groups, shared N/K/lda)
  auto launch = [&](int EPI, int N, int K, int lda,
                    const u16* A1, const u16* B1, const float* s1, u16* C1, int M1,
                    const u16* A2, const u16* B2, const float* s2, u16* C2, int M2,
                    const u16* A3, const u16* B3, const float* s3, u16* C3, int M3,
                    float* Cf) {
    int nbx = (M1 + M2 + M3) / 128, nby = N / 128;
    dim3 g(nbx * nby);
    switch (EPI) {
      case 0: gemm_bt<0><<<g, 256, 0, stream>>>(A1, B1, s1, Cf, C1, M1, N, K, lda, nbx, nby, A2, B2, s2, C2, M2, A3, B3, s3, C3, M3); break;
      case 1: gemm_bt<1><<<g, 256, 0, stream>>>(A1, B1, s1, Cf, C1, M1, N, K, lda, nbx, nby, A2, B2, s2, C2, M2, A3, B3, s3, C3, M3); break;
      case 2: gemm_bt<2><<<g, 256, 0, stream>>>(A1, B1, s1, Cf, C1, M1, N, K, lda, nbx, nby, A2, B2, s2, C2, M2, A3, B3, s3, C3, M3); break;
      default: gemm_bt<3><<<g, 256, 0, stream>>>(A1, B1, s1, Cf, C1, M1, N, K, lda, nbx, nby, A2, B2, s2, C2, M2, A3, B3, s3, C3, M3); break;
    }
  };
  const u16* Z = nullptr;

  for (int dg0 = 0; dg0 < 32; dg0 += dgc) {
    const float* xg = x + (size_t)dg0 * 2560 * 1024;
    long q0g = (long)dg0 * 320;

    pool_cvt<<<Tq, 256, 0, stream>>>(xg, Xb, Qp);

    // fused k1+v1 -> gelu -> Hb2 (Tc x 2048)
    launch(1, 2048, 1024, 1024, Xb, wb_kv1, b_kv1, Hb2, Tc,
           Z, Z, nullptr, nullptr, 0, Z, Z, nullptr, nullptr, 0, nullptr);

    // grouped k2 + v2 (strided halves of Hb2) -> Kb, Vb
    launch(0, 1024, 1024, 2048, Hb2, wb_k2, k_b2, Kb, Tc,
           Hb2 + 1024, wb_v2, v_b2, Vb, Tc, Z, Z, nullptr, nullptr, 0, nullptr);

    // fused LN(K) + LN(V)
    ln2_ip<<<2 * Tc, 256, 0, stream>>>(Kb, lnk_w, lnk_b, Vb, lnv_w, lnv_b, Tc);

    // q path: q-proj -> LN
    launch(3, 1024, 1024, 1024, Qp, wb_q, nullptr, QQ, Tq,
           Z, Z, nullptr, nullptr, 0, Z, Z, nullptr, nullptr, 0, nullptr);
    ln_ip<<<Tq, 256, 0, stream>>>(QQ, lnq_w, lnq_b);

    // grouped kh + vh + qkv_q (all N=1024, K=1024, lda=1024):
    //   kh: Kb @ in_w[C:2C]^T -> Xb ; vh: Vb @ in_w[2C:3C]^T -> Hb2 ;
    //   qh: QQ @ in_w[0:C]^T -> QHb
    launch(0, 1024, 1024, 1024, Kb, wb_in + CC, in_b + 1024, Xb, Tc,
           Vb, wb_in + 2 * CC, in_b + 2048, Hb2, Tc,
           QQ, wb_in, in_b, QHb, Tq, nullptr);

    attn_k<<<Tq, 256, 0, stream>>>(QHb, Xb, Hb2, Ob);

    // out-proj, then final MLP
    launch(0, 1024, 1024, 1024, Ob, wb_out, out_b, O2, Tq,
           Z, Z, nullptr, nullptr, 0, Z, Z, nullptr, nullptr, 0, nullptr);
    launch(1, 2048, 1024, 1024, O2, wb_m1, mlp_b1, Hm, Tq,
           Z, Z, nullptr, nullptr, 0, Z, Z, nullptr, nullptr, 0, nullptr);
    launch(2, 2048, 2048, 2048, Hm, wb_m2, mlp_b2, nullptr, Tq,
           Z, Z, nullptr, nullptr, 0, Z, Z, nullptr, nullptr, 0,
           out + q0g * 2048);
  }
}